// Round 3
// baseline (690.229 us; speedup 1.0000x reference)
//
#include <hip/hip_runtime.h>
#include <hip/hip_cooperative_groups.h>

namespace cg = cooperative_groups;

#define NN 50000
#define EE 600000
#define INF 256
#define HF 128
#define CEB ((EE + 255) / 256)    // 2344
#define GB ((NN + 63) / 64)       // 782 gemm tiles
#define NBCH ((NN + 255) / 256)   // 196 scan chunks

typedef __attribute__((ext_vector_type(8))) short short8;
typedef __attribute__((ext_vector_type(4))) float floatx4;

// ---------------- bf16 helpers ----------------
__device__ __forceinline__ unsigned short f32_to_bf16_rne(float x) {
    unsigned int u = __float_as_uint(x);
    unsigned int r = (u + 0x7FFFu + ((u >> 16) & 1u)) >> 16;
    return (unsigned short)r;
}
__device__ __forceinline__ float bf16_to_f32(unsigned short h) {
    return __uint_as_float(((unsigned int)h) << 16);
}
__device__ __forceinline__ float bf16lo_u32(unsigned int u) {
    return __uint_as_float(u << 16);
}
__device__ __forceinline__ float bf16hi_u32(unsigned int u) {
    return __uint_as_float(u & 0xFFFF0000u);
}
__device__ __forceinline__ void cvt_hilo8(float4 v0, float4 v1, short8& hs, short8& ls) {
    float x[8] = {v0.x, v0.y, v0.z, v0.w, v1.x, v1.y, v1.z, v1.w};
    union { short8 s; unsigned short u[8]; } H, L;
#pragma unroll
    for (int k = 0; k < 8; ++k) {
        unsigned short hi = f32_to_bf16_rne(x[k]);
        H.u[k] = hi;
        L.u[k] = f32_to_bf16_rne(x[k] - bf16_to_f32(hi));
    }
    hs = H.s;
    ls = L.s;
}

// ---------------- kernel argument bundle ----------------
struct Args {
    const float* in_feat; const int* row; const int* col;
    const float* lin_w; const float* lin_b;
    const float* conv_w; const float* conv_b;
    const float* root_emb; const float* ln_gamma; const float* ln_beta;
    float* out;
    float* deg_inv; float* dis;
    int* cnt; int* row_start; int* pos; int* bsum; int* csr_col;
    unsigned short* fl; unsigned short* fc;
    float* h0; unsigned short* hbf;
    unsigned short* agg_hi; unsigned short* agg_lo;
};

// ---------------- phase bodies (shared between mega + fallback) ----------------
__device__ __forceinline__ void prepack_one(const Args& a, int idx) {
    const float* src; unsigned short* dst; int K, c;
    if (idx < 8192) { src = a.lin_w; dst = a.fl; K = INF; c = idx; }
    else            { src = a.conv_w; dst = a.fc; K = HF; c = idx - 8192; }
    int lane = c & 63;
    int nt = (c >> 6) & 7;
    int hl = (c >> 9) & 1;
    int kc = c >> 10;
    int rw = nt * 16 + (lane & 15);
    int koff = kc * 32 + (lane >> 4) * 8;
    const float* p = &src[(size_t)rw * K + koff];
    float4 v0 = *reinterpret_cast<const float4*>(p);
    float4 v1 = *reinterpret_cast<const float4*>(p + 4);
    short8 hs, ls;
    cvt_hilo8(v0, v1, hs, ls);
    *reinterpret_cast<short8*>(&dst[(size_t)c * 8]) = hl ? ls : hs;
}

__device__ __forceinline__ void zero_prepack_body(const Args& a, int gtid, int T) {
    for (int i = gtid; i < NN; i += T) a.cnt[i] = 0;
    for (int i = gtid; i < 12288; i += T) prepack_one(a, i);
}

__device__ __forceinline__ void count_body(const Args& a, int gtid, int T) {
    for (int e = gtid; e < EE; e += T) a.pos[e] = atomicAdd(&a.cnt[a.row[e]], 1);
}

__device__ __forceinline__ void scanA_body(const Args& a, int* sdata) {
    int t = threadIdx.x;
    for (int c = blockIdx.x; c < NBCH; c += gridDim.x) {
        int i = c * 256 + t;
        sdata[t] = (i < NN) ? a.cnt[i] : 0;
        __syncthreads();
        for (int s = 128; s > 0; s >>= 1) {
            if (t < s) sdata[t] += sdata[t + s];
            __syncthreads();
        }
        if (t == 0) a.bsum[c] = sdata[0];
        __syncthreads();
    }
}

__device__ __forceinline__ void scanC_body(const Args& a, int* sb, int* sdata) {
    int t = threadIdx.x;
    for (int c = blockIdx.x; c < NBCH; c += gridDim.x) {
        sb[t] = (t < NBCH) ? a.bsum[t] : 0;
        __syncthreads();
        for (int s = 1; s < 256; s <<= 1) {
            int add = (t >= s) ? sb[t - s] : 0;
            __syncthreads();
            sb[t] += add;
            __syncthreads();
        }
        int base = sb[c] - a.bsum[c];
        int i = c * 256 + t;
        int v = (i < NN) ? a.cnt[i] : 0;
        sdata[t] = v;
        __syncthreads();
        for (int s = 1; s < 256; s <<= 1) {
            int add = (t >= s) ? sdata[t - s] : 0;
            __syncthreads();
            sdata[t] += add;
            __syncthreads();
        }
        if (i < NN) {
            a.row_start[i] = base + sdata[t] - v;
            float d = (float)(v + 1);
            a.deg_inv[i] = 1.0f / d;
            a.dis[i] = rsqrtf(d);
        }
        __syncthreads();
    }
    if (blockIdx.x == 0 && t == 0) a.row_start[NN] = EE;
}

__device__ __forceinline__ void fill_body(const Args& a, int gtid, int T) {
    for (int e = gtid; e < EE; e += T) {
        int pp = a.row_start[a.row[e]] + a.pos[e];
        __builtin_nontemporal_store(a.col[e], &a.csr_col[pp]);
    }
}

// one wave aggregates one node: agg = dis*sum(hbf[neighbors]) + deg_inv*h0, hi/lo bf16 out
__device__ __forceinline__ void agg_node(const Args& p, int wid, int lane) {
    int q = lane >> 4;
    int l16 = lane & 15;
    int s = p.row_start[wid];
    int e = p.row_start[wid + 1];
    float a0 = 0.f, a1 = 0.f, a2 = 0.f, a3 = 0.f, a4 = 0.f, a5 = 0.f, a6 = 0.f, a7 = 0.f;
    const unsigned short* hbf = p.hbf;
    if (e - s <= 16) {
        int j0 = s + q;
        bool p0 = j0 < e, p1 = j0 + 4 < e, p2 = j0 + 8 < e, p3 = j0 + 12 < e;
        int c0 = p0 ? p.csr_col[j0] : 0;
        int c1 = p1 ? p.csr_col[j0 + 4] : 0;
        int c2 = p2 ? p.csr_col[j0 + 8] : 0;
        int c3 = p3 ? p.csr_col[j0 + 12] : 0;
        uint4 z = make_uint4(0, 0, 0, 0);
        uint4 g0 = z, g1 = z, g2 = z, g3 = z;
        if (p0) g0 = *reinterpret_cast<const uint4*>(&hbf[(size_t)c0 * HF + l16 * 8]);
        if (p1) g1 = *reinterpret_cast<const uint4*>(&hbf[(size_t)c1 * HF + l16 * 8]);
        if (p2) g2 = *reinterpret_cast<const uint4*>(&hbf[(size_t)c2 * HF + l16 * 8]);
        if (p3) g3 = *reinterpret_cast<const uint4*>(&hbf[(size_t)c3 * HF + l16 * 8]);
        a0 = bf16lo_u32(g0.x) + bf16lo_u32(g1.x) + bf16lo_u32(g2.x) + bf16lo_u32(g3.x);
        a1 = bf16hi_u32(g0.x) + bf16hi_u32(g1.x) + bf16hi_u32(g2.x) + bf16hi_u32(g3.x);
        a2 = bf16lo_u32(g0.y) + bf16lo_u32(g1.y) + bf16lo_u32(g2.y) + bf16lo_u32(g3.y);
        a3 = bf16hi_u32(g0.y) + bf16hi_u32(g1.y) + bf16hi_u32(g2.y) + bf16hi_u32(g3.y);
        a4 = bf16lo_u32(g0.z) + bf16lo_u32(g1.z) + bf16lo_u32(g2.z) + bf16lo_u32(g3.z);
        a5 = bf16hi_u32(g0.z) + bf16hi_u32(g1.z) + bf16hi_u32(g2.z) + bf16hi_u32(g3.z);
        a6 = bf16lo_u32(g0.w) + bf16lo_u32(g1.w) + bf16lo_u32(g2.w) + bf16lo_u32(g3.w);
        a7 = bf16hi_u32(g0.w) + bf16hi_u32(g1.w) + bf16hi_u32(g2.w) + bf16hi_u32(g3.w);
    } else {
        float b0 = 0.f, b1 = 0.f, b2 = 0.f, b3 = 0.f, b4 = 0.f, b5 = 0.f, b6 = 0.f, b7 = 0.f;
        int j = s + q;
        for (; j + 4 < e; j += 8) {
            int c0 = p.csr_col[j];
            int c1 = p.csr_col[j + 4];
            uint4 h0 = *reinterpret_cast<const uint4*>(&hbf[(size_t)c0 * HF + l16 * 8]);
            uint4 h1 = *reinterpret_cast<const uint4*>(&hbf[(size_t)c1 * HF + l16 * 8]);
            a0 += bf16lo_u32(h0.x); a1 += bf16hi_u32(h0.x);
            a2 += bf16lo_u32(h0.y); a3 += bf16hi_u32(h0.y);
            a4 += bf16lo_u32(h0.z); a5 += bf16hi_u32(h0.z);
            a6 += bf16lo_u32(h0.w); a7 += bf16hi_u32(h0.w);
            b0 += bf16lo_u32(h1.x); b1 += bf16hi_u32(h1.x);
            b2 += bf16lo_u32(h1.y); b3 += bf16hi_u32(h1.y);
            b4 += bf16lo_u32(h1.z); b5 += bf16hi_u32(h1.z);
            b6 += bf16lo_u32(h1.w); b7 += bf16hi_u32(h1.w);
        }
        if (j < e) {
            int c0 = p.csr_col[j];
            uint4 h0 = *reinterpret_cast<const uint4*>(&hbf[(size_t)c0 * HF + l16 * 8]);
            a0 += bf16lo_u32(h0.x); a1 += bf16hi_u32(h0.x);
            a2 += bf16lo_u32(h0.y); a3 += bf16hi_u32(h0.y);
            a4 += bf16lo_u32(h0.z); a5 += bf16hi_u32(h0.z);
            a6 += bf16lo_u32(h0.w); a7 += bf16hi_u32(h0.w);
        }
        a0 += b0; a1 += b1; a2 += b2; a3 += b3;
        a4 += b4; a5 += b5; a6 += b6; a7 += b7;
    }
#pragma unroll
    for (int m = 16; m < 64; m <<= 1) {
        a0 += __shfl_xor(a0, m, 64);
        a1 += __shfl_xor(a1, m, 64);
        a2 += __shfl_xor(a2, m, 64);
        a3 += __shfl_xor(a3, m, 64);
        a4 += __shfl_xor(a4, m, 64);
        a5 += __shfl_xor(a5, m, 64);
        a6 += __shfl_xor(a6, m, 64);
        a7 += __shfl_xor(a7, m, 64);
    }
    if (q == 0) {
        float dn = p.dis[wid];
        float di = p.deg_inv[wid];
        float4 hA = *reinterpret_cast<const float4*>(&p.h0[(size_t)wid * HF + l16 * 8]);
        float4 hB = *reinterpret_cast<const float4*>(&p.h0[(size_t)wid * HF + l16 * 8 + 4]);
        float o[8];
        o[0] = fmaf(dn, a0, di * hA.x);
        o[1] = fmaf(dn, a1, di * hA.y);
        o[2] = fmaf(dn, a2, di * hA.z);
        o[3] = fmaf(dn, a3, di * hA.w);
        o[4] = fmaf(dn, a4, di * hB.x);
        o[5] = fmaf(dn, a5, di * hB.y);
        o[6] = fmaf(dn, a6, di * hB.z);
        o[7] = fmaf(dn, a7, di * hB.w);
        unsigned short hi[8], lo[8];
#pragma unroll
        for (int k = 0; k < 8; ++k) {
            hi[k] = f32_to_bf16_rne(o[k]);
            lo[k] = f32_to_bf16_rne(o[k] - bf16_to_f32(hi[k]));
        }
        uint4 hp, lp;
        hp.x = (unsigned)hi[0] | ((unsigned)hi[1] << 16);
        hp.y = (unsigned)hi[2] | ((unsigned)hi[3] << 16);
        hp.z = (unsigned)hi[4] | ((unsigned)hi[5] << 16);
        hp.w = (unsigned)hi[6] | ((unsigned)hi[7] << 16);
        lp.x = (unsigned)lo[0] | ((unsigned)lo[1] << 16);
        lp.y = (unsigned)lo[2] | ((unsigned)lo[3] << 16);
        lp.z = (unsigned)lo[4] | ((unsigned)lo[5] << 16);
        lp.w = (unsigned)lo[6] | ((unsigned)lo[7] << 16);
        *reinterpret_cast<uint4*>(&p.agg_hi[(size_t)wid * HF + l16 * 8]) = hp;
        *reinterpret_cast<uint4*>(&p.agg_lo[(size_t)wid * HF + l16 * 8]) = lp;
    }
}

// one 64-row output tile of the split-bf16 MFMA GEMM (+ per-MODE epilogue)
template <int K, int MODE>
__device__ __forceinline__ void gemm_tile(const Args& p, int bidx, unsigned short* WS) {
    constexpr int NKC = K / 32;
    const int t = threadIdx.x;
    const int wave = t >> 6;
    const int lane = t & 63;
    const int lrow = lane & 15;
    const int quad = lane >> 4;
    const int bm = bidx * 64;
    int arow = bm + wave * 16 + lrow;
    if (arow >= NN) arow = NN - 1;

    const unsigned short* Wf = (MODE == 0) ? p.fl : p.fc;

    floatx4 acc[8];
#pragma unroll
    for (int nt = 0; nt < 8; ++nt) acc[nt] = (floatx4){0.f, 0.f, 0.f, 0.f};

#pragma unroll
    for (int pp = 0; pp < NKC / 2; ++pp) {
        __syncthreads();   // also guards WS reuse across grid-stride tiles
        {
            const uint4* src = reinterpret_cast<const uint4*>(Wf + (size_t)pp * 16384);
            uint4* dstl = reinterpret_cast<uint4*>(WS);
#pragma unroll
            for (int i = 0; i < 8; ++i) dstl[t + 256 * i] = src[t + 256 * i];
        }
        __syncthreads();
#pragma unroll
        for (int k2 = 0; k2 < 2; ++k2) {
            int kc = pp * 2 + k2;
            short8 afh, afl;
            if (MODE == 0) {
                const float* ap = &p.in_feat[(size_t)arow * K + kc * 32 + quad * 8];
                float4 a0 = *reinterpret_cast<const float4*>(ap);
                float4 a1 = *reinterpret_cast<const float4*>(ap + 4);
                cvt_hilo8(a0, a1, afh, afl);
            } else {
                size_t ao = (size_t)arow * K + kc * 32 + quad * 8;
                afh = *reinterpret_cast<const short8*>(&p.agg_hi[ao]);
                afl = *reinterpret_cast<const short8*>(&p.agg_lo[ao]);
            }
            const unsigned short* wb = &WS[k2 * 8192 + lane * 8];
#pragma unroll
            for (int nt = 0; nt < 8; ++nt) {
                short8 bfh = *reinterpret_cast<const short8*>(wb + nt * 512);
                short8 bfl = *reinterpret_cast<const short8*>(wb + 4096 + nt * 512);
                acc[nt] = __builtin_amdgcn_mfma_f32_16x16x32_bf16(afh, bfh, acc[nt], 0, 0, 0);
                acc[nt] = __builtin_amdgcn_mfma_f32_16x16x32_bf16(afl, bfh, acc[nt], 0, 0, 0);
                acc[nt] = __builtin_amdgcn_mfma_f32_16x16x32_bf16(afh, bfl, acc[nt], 0, 0, 0);
            }
        }
    }

    const float* bias = (MODE == 0) ? p.lin_b : p.conv_b;
    float* C = (MODE == 2) ? p.out : p.h0;

    float cb[8], rt[8], gm[8], bt[8];
#pragma unroll
    for (int nt = 0; nt < 8; ++nt) {
        int colh = nt * 16 + lrow;
        cb[nt] = bias[colh];
        if (MODE >= 1) rt[nt] = p.root_emb[colh];
        if (MODE == 1) { gm[nt] = p.ln_gamma[HF + colh]; bt[nt] = p.ln_beta[HF + colh]; }
    }

#pragma unroll
    for (int r = 0; r < 4; ++r) {
        int grow = bm + wave * 16 + quad * 4 + r;
        bool ok = (grow < NN);
        int gr = ok ? grow : NN - 1;
        float x[8];
        if (MODE == 0) {
#pragma unroll
            for (int nt = 0; nt < 8; ++nt) x[nt] = acc[nt][r] + cb[nt];
        } else {
            float di = p.deg_inv[gr];
            float hv[8];
#pragma unroll
            for (int nt = 0; nt < 8; ++nt) hv[nt] = p.h0[(size_t)gr * HF + nt * 16 + lrow];
#pragma unroll
            for (int nt = 0; nt < 8; ++nt) {
                float v = acc[nt][r] + cb[nt] + fmaxf(hv[nt] + rt[nt], 0.f) * di;
                x[nt] = (MODE == 1) ? v + hv[nt] : v;
            }
        }
        if (MODE == 1) {
            float s = 0.f;
#pragma unroll
            for (int nt = 0; nt < 8; ++nt) s += x[nt];
#pragma unroll
            for (int m = 1; m < 16; m <<= 1) s += __shfl_xor(s, m, 64);
            float mu = s * (1.0f / HF);
            float var = 0.f;
#pragma unroll
            for (int nt = 0; nt < 8; ++nt) { float d = x[nt] - mu; var += d * d; }
#pragma unroll
            for (int m = 1; m < 16; m <<= 1) var += __shfl_xor(var, m, 64);
            float rs = rsqrtf(var * (1.0f / HF) + 1e-5f);
            float ds = p.dis[gr];
            if (ok) {
#pragma unroll
                for (int nt = 0; nt < 8; ++nt) {
                    int colh = nt * 16 + lrow;
                    float y = fmaxf((x[nt] - mu) * rs * gm[nt] + bt[nt], 0.f);
                    C[(size_t)grow * HF + colh] = y;
                    p.hbf[(size_t)grow * HF + colh] = f32_to_bf16_rne(ds * y);
                }
            }
        } else if (MODE == 0) {
            if (ok) {
                float ds = p.dis[grow];
#pragma unroll
                for (int nt = 0; nt < 8; ++nt) {
                    int colh = nt * 16 + lrow;
                    C[(size_t)grow * HF + colh] = x[nt];
                    p.hbf[(size_t)grow * HF + colh] = f32_to_bf16_rne(ds * x[nt]);
                }
            }
        } else {
            if (ok) {
#pragma unroll
                for (int nt = 0; nt < 8; ++nt)
                    C[(size_t)grow * HF + nt * 16 + lrow] = x[nt];
            }
        }
    }
}

// ---------------- the cooperative mega-kernel: whole chain, 1 launch, 8 grid syncs ----
__global__ __launch_bounds__(256) void mega(Args a) {
    cg::grid_group grid = cg::this_grid();
    extern __shared__ __align__(16) char smem[];
    unsigned short* WS = reinterpret_cast<unsigned short*>(smem);
    int* si = reinterpret_cast<int*>(smem);
    const int T = gridDim.x * blockDim.x;
    const int gtid = blockIdx.x * blockDim.x + threadIdx.x;
    const int gwave = gtid >> 6;
    const int nwave = T >> 6;
    const int lane = threadIdx.x & 63;

    // P1: zero degree counters + prepack both weight matrices to bf16 hi/lo
    zero_prepack_body(a, gtid, T);
    grid.sync();
    // P2: degree count + per-edge rank
    count_body(a, gtid, T);
    grid.sync();
    // P3: per-chunk sums
    scanA_body(a, si);
    grid.sync();
    // P4: exclusive scan -> row_start, deg_inv, dis
    scanC_body(a, si, si + 256);
    grid.sync();
    // P5: CSR fill (atomic-free) + GEMM0 (h0 = in_feat @ lin_w.T + b, bf16 copy)
    fill_body(a, gtid, T);
    for (int b = blockIdx.x; b < GB; b += gridDim.x) gemm_tile<INF, 0>(a, b, WS);
    grid.sync();
    // P6: aggregate step 0 (one wave per node, wave-stride)
    for (int nd = gwave; nd < NN; nd += nwave) agg_node(a, nd, lane);
    grid.sync();
    // P7: GEMM1 (conv + residual/LN/ReLU epilogue, h0 in place + hbf refresh)
    for (int b = blockIdx.x; b < GB; b += gridDim.x) gemm_tile<HF, 1>(a, b, WS);
    grid.sync();
    // P8: aggregate step 1
    for (int nd = gwave; nd < NN; nd += nwave) agg_node(a, nd, lane);
    grid.sync();
    // P9: GEMM2 (conv + combine epilogue -> out)
    for (int b = blockIdx.x; b < GB; b += gridDim.x) gemm_tile<HF, 2>(a, b, WS);
}

// ---------------- fallback wrappers (non-cooperative chain) ----------------
__global__ void k_pre(Args a)   { zero_prepack_body(a, blockIdx.x * blockDim.x + threadIdx.x, gridDim.x * blockDim.x); }
__global__ void k_count(Args a) { count_body(a, blockIdx.x * blockDim.x + threadIdx.x, gridDim.x * blockDim.x); }
__global__ void k_scanA(Args a) { extern __shared__ __align__(16) char s[]; scanA_body(a, (int*)s); }
__global__ void k_scanC(Args a) { extern __shared__ __align__(16) char s[]; scanC_body(a, (int*)s, (int*)s + 256); }
__global__ void k_fill(Args a)  { fill_body(a, blockIdx.x * blockDim.x + threadIdx.x, gridDim.x * blockDim.x); }
__global__ void k_agg(Args a) {
    int gw = (blockIdx.x * blockDim.x + threadIdx.x) >> 6;
    int nw = (gridDim.x * blockDim.x) >> 6;
    int lane = threadIdx.x & 63;
    for (int nd = gw; nd < NN; nd += nw) agg_node(a, nd, lane);
}
template <int K, int MODE>
__global__ __launch_bounds__(256) void k_gemm(Args a) {
    extern __shared__ __align__(16) char s[];
    unsigned short* WS = reinterpret_cast<unsigned short*>(s);
    for (int b = blockIdx.x; b < GB; b += gridDim.x) gemm_tile<K, MODE>(a, b, WS);
}

extern "C" void kernel_launch(void* const* d_in, const int* in_sizes, int n_in,
                              void* d_out, int out_size, void* d_ws, size_t ws_size,
                              hipStream_t stream) {
    const int N = NN, E = EE;
    Args a;
    a.in_feat = (const float*)d_in[0];
    a.row = (const int*)d_in[1];
    a.col = (const int*)d_in[2];
    a.lin_w = (const float*)d_in[3];
    a.lin_b = (const float*)d_in[4];
    a.conv_w = (const float*)d_in[5];
    a.conv_b = (const float*)d_in[6];
    a.root_emb = (const float*)d_in[7];
    a.ln_gamma = (const float*)d_in[8];
    a.ln_beta = (const float*)d_in[9];
    a.out = (float*)d_out;

    // workspace layout (4B units); all segments kept 16B-aligned
    float* ws = (float*)d_ws;
    size_t o = 0;
    a.deg_inv = ws + o; o += N;
    a.dis = ws + o; o += N;
    a.cnt = (int*)(ws + o); o += N;
    a.row_start = (int*)(ws + o); o += N + 4;
    a.pos = (int*)(ws + o); o += E;
    a.bsum = (int*)(ws + o); o += 256;
    a.csr_col = (int*)(ws + o); o += E;
    o = (o + 3) & ~(size_t)3;
    a.fl = (unsigned short*)(ws + o); o += 32768;   // 65536 ushort (128KB)
    a.fc = (unsigned short*)(ws + o); o += 16384;   // 32768 ushort (64KB)
    a.h0 = ws + o; o += (size_t)N * HF;
    a.hbf = (unsigned short*)(ws + o); o += (size_t)N * HF / 2;
    a.agg_hi = (unsigned short*)(ws + o); o += (size_t)N * HF / 2;
    a.agg_lo = (unsigned short*)(ws + o); o += (size_t)N * HF / 2;

    constexpr unsigned int SHMEM = 32768;

    // one-time cooperative capacity query (host-side, graph-capture-safe)
    static int nblk = 0;
    static bool coop_ok = true;
    if (nblk == 0) {
        int dev = 0;
        hipGetDevice(&dev);
        int cus = 0;
        hipError_t e0 = hipDeviceGetAttribute(&cus, hipDeviceAttributeMultiprocessorCount, dev);
        int maxb = 0;
        hipError_t e1 = hipOccupancyMaxActiveBlocksPerMultiprocessor(&maxb, mega, 256, (size_t)SHMEM);
        if (e0 != hipSuccess || e1 != hipSuccess || cus < 1 || maxb < 1) {
            coop_ok = false;
            nblk = -1;
        } else {
            if (maxb > 5) maxb = 5;   // cap: more co-resident blocks only adds sync cost
            nblk = cus * maxb;
        }
    }

    if (coop_ok) {
        void* args[] = { (void*)&a };
        hipError_t err = hipLaunchCooperativeKernel(
            reinterpret_cast<const void*>(&mega), dim3(nblk), dim3(256), args, SHMEM, stream);
        if (err == hipSuccess) return;
        coop_ok = false;   // fall through to non-cooperative chain
    }

    // ---------------- fallback: separate-launch chain (round-0 structure) ----------------
    k_pre<<<256, 256, 0, stream>>>(a);
    k_count<<<CEB, 256, 0, stream>>>(a);
    k_scanA<<<NBCH, 256, 2048, stream>>>(a);
    k_scanC<<<NBCH, 256, 2048, stream>>>(a);
    k_fill<<<CEB, 256, 0, stream>>>(a);
    k_gemm<INF, 0><<<GB, 256, SHMEM, stream>>>(a);
    k_agg<<<(N + 3) / 4, 256, 0, stream>>>(a);
    k_gemm<HF, 1><<<GB, 256, SHMEM, stream>>>(a);
    k_agg<<<(N + 3) / 4, 256, 0, stream>>>(a);
    k_gemm<HF, 2><<<GB, 256, SHMEM, stream>>>(a);
}

// Round 5
// 285.517 us; speedup vs baseline: 2.4175x; 2.4175x over previous
//
#include <hip/hip_runtime.h>

#define NN 50000
#define EE 600000
#define INF 256
#define HF 128
#define CEB ((EE + 255) / 256)    // 2344 edge blocks
#define GB ((NN + 63) / 64)       // 782 gemm tiles
#define NBCH ((NN + 255) / 256)   // 196 scan chunks

typedef __attribute__((ext_vector_type(8))) short short8;
typedef __attribute__((ext_vector_type(4))) float floatx4;

// ---------------- bf16 helpers ----------------
__device__ __forceinline__ unsigned short f32_to_bf16_rne(float x) {
    unsigned int u = __float_as_uint(x);
    unsigned int r = (u + 0x7FFFu + ((u >> 16) & 1u)) >> 16;
    return (unsigned short)r;
}
__device__ __forceinline__ float bf16_to_f32(unsigned short h) {
    return __uint_as_float(((unsigned int)h) << 16);
}
__device__ __forceinline__ float bf16lo_u32(unsigned int u) {
    return __uint_as_float(u << 16);
}
__device__ __forceinline__ float bf16hi_u32(unsigned int u) {
    return __uint_as_float(u & 0xFFFF0000u);
}
__device__ __forceinline__ void cvt_hilo8(float4 v0, float4 v1, short8& hs, short8& ls) {
    float x[8] = {v0.x, v0.y, v0.z, v0.w, v1.x, v1.y, v1.z, v1.w};
    union { short8 s; unsigned short u[8]; } H, L;
#pragma unroll
    for (int k = 0; k < 8; ++k) {
        unsigned short hi = f32_to_bf16_rne(x[k]);
        H.u[k] = hi;
        L.u[k] = f32_to_bf16_rne(x[k] - bf16_to_f32(hi));
    }
    hs = H.s;
    ls = L.s;
}

// ---------------- scan phase1: per-chunk sums of cnt ----------------
__global__ void scan_phase1(const int* __restrict__ cnt, int* __restrict__ bsum, int n) {
    __shared__ int sdata[256];
    int t = threadIdx.x;
    int i = blockIdx.x * 256 + t;
    sdata[t] = (i < n) ? cnt[i] : 0;
    __syncthreads();
    for (int s = 128; s > 0; s >>= 1) {
        if (t < s) sdata[t] += sdata[t + s];
        __syncthreads();
    }
    if (t == 0) bsum[blockIdx.x] = sdata[0];
}

// ---------------- scan phase2+3 fused (+ finalize deg_inv/dis) ----------------
__global__ void scan_phase3(const int* __restrict__ cnt, const int* __restrict__ bsum,
                            int* __restrict__ row_start,
                            float* __restrict__ deg_inv, float* __restrict__ dis,
                            int n, int nb, int E) {
    __shared__ int sb[256];
    __shared__ int sdata[256];
    int t = threadIdx.x;
    sb[t] = (t < nb) ? bsum[t] : 0;
    __syncthreads();
    for (int s = 1; s < 256; s <<= 1) {
        int add = (t >= s) ? sb[t - s] : 0;
        __syncthreads();
        sb[t] += add;
        __syncthreads();
    }
    int base = sb[blockIdx.x] - bsum[blockIdx.x];
    int i = blockIdx.x * 256 + t;
    int v = (i < n) ? cnt[i] : 0;
    sdata[t] = v;
    __syncthreads();
    for (int s = 1; s < 256; s <<= 1) {
        int add = (t >= s) ? sdata[t - s] : 0;
        __syncthreads();
        sdata[t] += add;
        __syncthreads();
    }
    if (i < n) {
        row_start[i] = base + sdata[t] - v;
        float d = (float)(v + 1);
        deg_inv[i] = 1.0f / d;
        dis[i] = rsqrtf(d);
    }
    if (blockIdx.x == 0 && t == 0) row_start[n] = E;
}

// ---------------- atomic-free CSR fill ----------------
__global__ void fill_csr(const int* __restrict__ row, const int* __restrict__ col,
                         const int* __restrict__ row_start, const int* __restrict__ pos,
                         int* __restrict__ csr_col, int E) {
    int e = blockIdx.x * blockDim.x + threadIdx.x;
    if (e < E) {
        int p = row_start[row[e]] + pos[e];
        __builtin_nontemporal_store(col[e], &csr_col[p]);
    }
}

// ---------------- split-bf16 MFMA GEMM tile; W staged f32->hi/lo bf16 inline -------
// hbf convention: UNSCALED bf16(h). dis factors are applied in aggregate only.
// MODE 0: A = in_feat f32 (cvt on the fly), epilogue: +bias -> h0 + hbf
// MODE 1: A = agg hi/lo bf16, epilogue: conv_b + root/deg + residual + LN + ReLU -> h0 + hbf
// MODE 2: A = agg hi/lo bf16, epilogue: conv_b + root/deg -> out
template <int K, int MODE>
__device__ __forceinline__ void gemm_tile(
    int bidx,
    const float* __restrict__ Af,
    const unsigned short* __restrict__ Ahg, const unsigned short* __restrict__ Alg,
    const float* __restrict__ Wsrc,
    const float* __restrict__ bias,
    float* __restrict__ C, unsigned short* __restrict__ Cbf,
    const float* __restrict__ h, const float* __restrict__ deg_inv,
    const float* __restrict__ root,
    const float* __restrict__ gamma, const float* __restrict__ beta,
    unsigned short* WS, int M) {
    constexpr int NKC = K / 32;
    const int t = threadIdx.x;
    const int wave = t >> 6;
    const int lane = t & 63;
    const int lrow = lane & 15;
    const int quad = lane >> 4;
    const int bm = bidx * 64;
    int arow = bm + wave * 16 + lrow;
    if (arow >= M) arow = M - 1;   // clamp; stores are predicated

    floatx4 acc[8];
#pragma unroll
    for (int nt = 0; nt < 8; ++nt) acc[nt] = (floatx4){0.f, 0.f, 0.f, 0.f};

#pragma unroll
    for (int pp = 0; pp < NKC / 2; ++pp) {
        if (pp) __syncthreads();
        // stage W chunk (2 kc) from f32, converting to hi/lo bf16: 1024 fragment units
#pragma unroll
        for (int u0 = 0; u0 < 4; ++u0) {
            int u = t + u0 * 256;
            int kc2 = u >> 9;
            int nt = (u >> 6) & 7;
            int ln = u & 63;
            int rw = nt * 16 + (ln & 15);
            int koff = (pp * 2 + kc2) * 32 + (ln >> 4) * 8;
            const float* p = &Wsrc[(size_t)rw * K + koff];
            float4 v0 = *reinterpret_cast<const float4*>(p);
            float4 v1 = *reinterpret_cast<const float4*>(p + 4);
            short8 hs, ls;
            cvt_hilo8(v0, v1, hs, ls);
            *reinterpret_cast<short8*>(&WS[kc2 * 8192 + nt * 512 + ln * 8]) = hs;
            *reinterpret_cast<short8*>(&WS[kc2 * 8192 + 4096 + nt * 512 + ln * 8]) = ls;
        }
        __syncthreads();
#pragma unroll
        for (int k2 = 0; k2 < 2; ++k2) {
            int kc = pp * 2 + k2;
            short8 afh, afl;
            if (MODE == 0) {
                const float* ap = &Af[(size_t)arow * K + kc * 32 + quad * 8];
                float4 a0 = *reinterpret_cast<const float4*>(ap);
                float4 a1 = *reinterpret_cast<const float4*>(ap + 4);
                cvt_hilo8(a0, a1, afh, afl);
            } else {
                size_t ao = (size_t)arow * K + kc * 32 + quad * 8;
                afh = *reinterpret_cast<const short8*>(&Ahg[ao]);
                afl = *reinterpret_cast<const short8*>(&Alg[ao]);
            }
            const unsigned short* wb = &WS[k2 * 8192 + lane * 8];
#pragma unroll
            for (int nt = 0; nt < 8; ++nt) {
                short8 bfh = *reinterpret_cast<const short8*>(wb + nt * 512);
                short8 bfl = *reinterpret_cast<const short8*>(wb + 4096 + nt * 512);
                acc[nt] = __builtin_amdgcn_mfma_f32_16x16x32_bf16(afh, bfh, acc[nt], 0, 0, 0);
                acc[nt] = __builtin_amdgcn_mfma_f32_16x16x32_bf16(afl, bfh, acc[nt], 0, 0, 0);
                acc[nt] = __builtin_amdgcn_mfma_f32_16x16x32_bf16(afh, bfl, acc[nt], 0, 0, 0);
            }
        }
    }

    float cb[8], rt[8], gm[8], bt[8];
#pragma unroll
    for (int nt = 0; nt < 8; ++nt) {
        int colh = nt * 16 + lrow;
        cb[nt] = bias[colh];
        if (MODE >= 1) rt[nt] = root[colh];
        if (MODE == 1) { gm[nt] = gamma[colh]; bt[nt] = beta[colh]; }
    }

#pragma unroll
    for (int r = 0; r < 4; ++r) {
        int grow = bm + wave * 16 + quad * 4 + r;
        bool ok = (grow < M);
        int gr = ok ? grow : M - 1;
        float x[8];
        if (MODE == 0) {
#pragma unroll
            for (int nt = 0; nt < 8; ++nt) x[nt] = acc[nt][r] + cb[nt];
        } else {
            float di = deg_inv[gr];
            float hv[8];
#pragma unroll
            for (int nt = 0; nt < 8; ++nt) hv[nt] = h[(size_t)gr * HF + nt * 16 + lrow];
#pragma unroll
            for (int nt = 0; nt < 8; ++nt) {
                float v = acc[nt][r] + cb[nt] + fmaxf(hv[nt] + rt[nt], 0.f) * di;
                x[nt] = (MODE == 1) ? v + hv[nt] : v;
            }
        }
        if (MODE == 1) {
            float s = 0.f;
#pragma unroll
            for (int nt = 0; nt < 8; ++nt) s += x[nt];
#pragma unroll
            for (int m = 1; m < 16; m <<= 1) s += __shfl_xor(s, m, 64);
            float mu = s * (1.0f / HF);
            float var = 0.f;
#pragma unroll
            for (int nt = 0; nt < 8; ++nt) { float d = x[nt] - mu; var += d * d; }
#pragma unroll
            for (int m = 1; m < 16; m <<= 1) var += __shfl_xor(var, m, 64);
            float rs = rsqrtf(var * (1.0f / HF) + 1e-5f);
            if (ok) {
#pragma unroll
                for (int nt = 0; nt < 8; ++nt) {
                    int colh = nt * 16 + lrow;
                    float y = fmaxf((x[nt] - mu) * rs * gm[nt] + bt[nt], 0.f);
                    C[(size_t)grow * HF + colh] = y;
                    Cbf[(size_t)grow * HF + colh] = f32_to_bf16_rne(y);
                }
            }
        } else if (MODE == 0) {
            if (ok) {
#pragma unroll
                for (int nt = 0; nt < 8; ++nt) {
                    int colh = nt * 16 + lrow;
                    C[(size_t)grow * HF + colh] = x[nt];
                    Cbf[(size_t)grow * HF + colh] = f32_to_bf16_rne(x[nt]);
                }
            }
        } else {
            if (ok) {
#pragma unroll
                for (int nt = 0; nt < 8; ++nt)
                    C[(size_t)grow * HF + nt * 16 + lrow] = x[nt];
            }
        }
    }
}

// ---------------- L1: gemm0 (fully independent now) overlapped with degree count ------
__global__ __launch_bounds__(256) void gemm0_count(
    const float* __restrict__ in_feat, const float* __restrict__ lin_w,
    const float* __restrict__ lin_b,
    float* __restrict__ h0, unsigned short* __restrict__ hbf,
    const int* __restrict__ row, int* __restrict__ cnt, int* __restrict__ pos) {
    __shared__ unsigned short WS[2 * 8192];
    int b = blockIdx.x;
    if (b < GB) {
        gemm_tile<INF, 0>(b, in_feat, nullptr, nullptr, lin_w, lin_b,
                          h0, hbf, nullptr, nullptr, nullptr,
                          nullptr, nullptr, WS, NN);
        return;
    }
    int e = (b - GB) * 256 + threadIdx.x;
    if (e < EE) pos[e] = atomicAdd(&cnt[row[e]], 1);
}

template <int MODE>
__global__ __launch_bounds__(256) void gemm_conv(
    const unsigned short* __restrict__ agg_hi, const unsigned short* __restrict__ agg_lo,
    const float* __restrict__ conv_w, const float* __restrict__ conv_b,
    float* __restrict__ C, unsigned short* __restrict__ Cbf,
    const float* __restrict__ h, const float* __restrict__ deg_inv,
    const float* __restrict__ root,
    const float* __restrict__ gamma, const float* __restrict__ beta) {
    __shared__ unsigned short WS[2 * 8192];
    gemm_tile<HF, MODE>(blockIdx.x, nullptr, agg_hi, agg_lo, conv_w, conv_b,
                        C, Cbf, h, deg_inv, root, gamma, beta, WS, NN);
}

// ---------------- aggregate: agg = dis[t]*sum_e dis[c]*hbf[c] + deg_inv[t]*h[t] -------
__global__ void aggregate(const int* __restrict__ row_start, const int* __restrict__ csr_col,
                          const float* __restrict__ dis, const float* __restrict__ deg_inv,
                          const float* __restrict__ h, const unsigned short* __restrict__ hbf,
                          unsigned short* __restrict__ agg_hi, unsigned short* __restrict__ agg_lo,
                          int n) {
    int wid = (blockIdx.x * blockDim.x + threadIdx.x) >> 6;
    int lane = threadIdx.x & 63;
    if (wid >= n) return;
    int q = lane >> 4;
    int l16 = lane & 15;
    int s = row_start[wid];
    int e = row_start[wid + 1];
    float a0 = 0.f, a1 = 0.f, a2 = 0.f, a3 = 0.f, a4 = 0.f, a5 = 0.f, a6 = 0.f, a7 = 0.f;
    if (e - s <= 16) {
        int j0 = s + q;
        bool p0 = j0 < e, p1 = j0 + 4 < e, p2 = j0 + 8 < e, p3 = j0 + 12 < e;
        int c0 = p0 ? csr_col[j0] : 0;
        int c1 = p1 ? csr_col[j0 + 4] : 0;
        int c2 = p2 ? csr_col[j0 + 8] : 0;
        int c3 = p3 ? csr_col[j0 + 12] : 0;
        float d0 = dis[c0], d1 = dis[c1], d2 = dis[c2], d3 = dis[c3];
        uint4 z = make_uint4(0, 0, 0, 0);
        uint4 g0 = z, g1 = z, g2 = z, g3 = z;
        if (p0) g0 = *reinterpret_cast<const uint4*>(&hbf[(size_t)c0 * HF + l16 * 8]);
        if (p1) g1 = *reinterpret_cast<const uint4*>(&hbf[(size_t)c1 * HF + l16 * 8]);
        if (p2) g2 = *reinterpret_cast<const uint4*>(&hbf[(size_t)c2 * HF + l16 * 8]);
        if (p3) g3 = *reinterpret_cast<const uint4*>(&hbf[(size_t)c3 * HF + l16 * 8]);
        a0 = d0 * bf16lo_u32(g0.x) + d1 * bf16lo_u32(g1.x) + d2 * bf16lo_u32(g2.x) + d3 * bf16lo_u32(g3.x);
        a1 = d0 * bf16hi_u32(g0.x) + d1 * bf16hi_u32(g1.x) + d2 * bf16hi_u32(g2.x) + d3 * bf16hi_u32(g3.x);
        a2 = d0 * bf16lo_u32(g0.y) + d1 * bf16lo_u32(g1.y) + d2 * bf16lo_u32(g2.y) + d3 * bf16lo_u32(g3.y);
        a3 = d0 * bf16hi_u32(g0.y) + d1 * bf16hi_u32(g1.y) + d2 * bf16hi_u32(g2.y) + d3 * bf16hi_u32(g3.y);
        a4 = d0 * bf16lo_u32(g0.z) + d1 * bf16lo_u32(g1.z) + d2 * bf16lo_u32(g2.z) + d3 * bf16lo_u32(g3.z);
        a5 = d0 * bf16hi_u32(g0.z) + d1 * bf16hi_u32(g1.z) + d2 * bf16hi_u32(g2.z) + d3 * bf16hi_u32(g3.z);
        a6 = d0 * bf16lo_u32(g0.w) + d1 * bf16lo_u32(g1.w) + d2 * bf16lo_u32(g2.w) + d3 * bf16lo_u32(g3.w);
        a7 = d0 * bf16hi_u32(g0.w) + d1 * bf16hi_u32(g1.w) + d2 * bf16hi_u32(g2.w) + d3 * bf16hi_u32(g3.w);
    } else {
        float b0 = 0.f, b1 = 0.f, b2 = 0.f, b3 = 0.f, b4 = 0.f, b5 = 0.f, b6 = 0.f, b7 = 0.f;
        int j = s + q;
        for (; j + 4 < e; j += 8) {
            int c0 = csr_col[j];
            int c1 = csr_col[j + 4];
            float d0 = dis[c0];
            float d1 = dis[c1];
            uint4 h0 = *reinterpret_cast<const uint4*>(&hbf[(size_t)c0 * HF + l16 * 8]);
            uint4 h1 = *reinterpret_cast<const uint4*>(&hbf[(size_t)c1 * HF + l16 * 8]);
            a0 = fmaf(d0, bf16lo_u32(h0.x), a0); a1 = fmaf(d0, bf16hi_u32(h0.x), a1);
            a2 = fmaf(d0, bf16lo_u32(h0.y), a2); a3 = fmaf(d0, bf16hi_u32(h0.y), a3);
            a4 = fmaf(d0, bf16lo_u32(h0.z), a4); a5 = fmaf(d0, bf16hi_u32(h0.z), a5);
            a6 = fmaf(d0, bf16lo_u32(h0.w), a6); a7 = fmaf(d0, bf16hi_u32(h0.w), a7);
            b0 = fmaf(d1, bf16lo_u32(h1.x), b0); b1 = fmaf(d1, bf16hi_u32(h1.x), b1);
            b2 = fmaf(d1, bf16lo_u32(h1.y), b2); b3 = fmaf(d1, bf16hi_u32(h1.y), b3);
            b4 = fmaf(d1, bf16lo_u32(h1.z), b4); b5 = fmaf(d1, bf16hi_u32(h1.z), b5);
            b6 = fmaf(d1, bf16lo_u32(h1.w), b6); b7 = fmaf(d1, bf16hi_u32(h1.w), b7);
        }
        if (j < e) {
            int c0 = csr_col[j];
            float d0 = dis[c0];
            uint4 h0 = *reinterpret_cast<const uint4*>(&hbf[(size_t)c0 * HF + l16 * 8]);
            a0 = fmaf(d0, bf16lo_u32(h0.x), a0); a1 = fmaf(d0, bf16hi_u32(h0.x), a1);
            a2 = fmaf(d0, bf16lo_u32(h0.y), a2); a3 = fmaf(d0, bf16hi_u32(h0.y), a3);
            a4 = fmaf(d0, bf16lo_u32(h0.z), a4); a5 = fmaf(d0, bf16hi_u32(h0.z), a5);
            a6 = fmaf(d0, bf16lo_u32(h0.w), a6); a7 = fmaf(d0, bf16hi_u32(h0.w), a7);
        }
        a0 += b0; a1 += b1; a2 += b2; a3 += b3;
        a4 += b4; a5 += b5; a6 += b6; a7 += b7;
    }
#pragma unroll
    for (int m = 16; m < 64; m <<= 1) {
        a0 += __shfl_xor(a0, m, 64);
        a1 += __shfl_xor(a1, m, 64);
        a2 += __shfl_xor(a2, m, 64);
        a3 += __shfl_xor(a3, m, 64);
        a4 += __shfl_xor(a4, m, 64);
        a5 += __shfl_xor(a5, m, 64);
        a6 += __shfl_xor(a6, m, 64);
        a7 += __shfl_xor(a7, m, 64);
    }
    if (q == 0) {
        float dn = dis[wid];
        float di = deg_inv[wid];
        float4 hA = *reinterpret_cast<const float4*>(&h[(size_t)wid * HF + l16 * 8]);
        float4 hB = *reinterpret_cast<const float4*>(&h[(size_t)wid * HF + l16 * 8 + 4]);
        float o[8];
        o[0] = fmaf(dn, a0, di * hA.x);
        o[1] = fmaf(dn, a1, di * hA.y);
        o[2] = fmaf(dn, a2, di * hA.z);
        o[3] = fmaf(dn, a3, di * hA.w);
        o[4] = fmaf(dn, a4, di * hB.x);
        o[5] = fmaf(dn, a5, di * hB.y);
        o[6] = fmaf(dn, a6, di * hB.z);
        o[7] = fmaf(dn, a7, di * hB.w);
        unsigned short hi[8], lo[8];
#pragma unroll
        for (int k = 0; k < 8; ++k) {
            hi[k] = f32_to_bf16_rne(o[k]);
            lo[k] = f32_to_bf16_rne(o[k] - bf16_to_f32(hi[k]));
        }
        uint4 hp, lp;
        hp.x = (unsigned)hi[0] | ((unsigned)hi[1] << 16);
        hp.y = (unsigned)hi[2] | ((unsigned)hi[3] << 16);
        hp.z = (unsigned)hi[4] | ((unsigned)hi[5] << 16);
        hp.w = (unsigned)hi[6] | ((unsigned)hi[7] << 16);
        lp.x = (unsigned)lo[0] | ((unsigned)lo[1] << 16);
        lp.y = (unsigned)lo[2] | ((unsigned)lo[3] << 16);
        lp.z = (unsigned)lo[4] | ((unsigned)lo[5] << 16);
        lp.w = (unsigned)lo[6] | ((unsigned)lo[7] << 16);
        *reinterpret_cast<uint4*>(&agg_hi[(size_t)wid * HF + l16 * 8]) = hp;
        *reinterpret_cast<uint4*>(&agg_lo[(size_t)wid * HF + l16 * 8]) = lp;
    }
}

extern "C" void kernel_launch(void* const* d_in, const int* in_sizes, int n_in,
                              void* d_out, int out_size, void* d_ws, size_t ws_size,
                              hipStream_t stream) {
    const int N = NN, E = EE;
    const float* in_feat = (const float*)d_in[0];
    const int* row = (const int*)d_in[1];
    const int* col = (const int*)d_in[2];
    const float* lin_w = (const float*)d_in[3];
    const float* lin_b = (const float*)d_in[4];
    const float* conv_w = (const float*)d_in[5];
    const float* conv_b = (const float*)d_in[6];
    const float* root_emb = (const float*)d_in[7];
    const float* ln_gamma = (const float*)d_in[8];
    const float* ln_beta = (const float*)d_in[9];
    float* out = (float*)d_out;

    // workspace layout (4B units); all segments kept 16B-aligned
    float* ws = (float*)d_ws;
    size_t o = 0;
    float* deg_inv = ws + o; o += N;
    float* dis = ws + o; o += N;
    int* cnt = (int*)(ws + o); o += N;
    int* row_start = (int*)(ws + o); o += N + 4;
    int* pos = (int*)(ws + o); o += E;
    int* bsum = (int*)(ws + o); o += 256;
    int* csr_col = (int*)(ws + o); o += E;
    float* h0 = ws + o; o += (size_t)N * HF;
    unsigned short* hbf = (unsigned short*)(ws + o); o += (size_t)N * HF / 2;
    unsigned short* agg_hi = (unsigned short*)(ws + o); o += (size_t)N * HF / 2;
    unsigned short* agg_lo = (unsigned short*)(ws + o); o += (size_t)N * HF / 2;

    const int WB = (N + 3) / 4;   // 12500 aggregate blocks (4 waves each)

    hipMemsetAsync(cnt, 0, N * sizeof(int), stream);

    // L1: gemm0 (h0 = in_feat @ lin_w.T + b, + unscaled bf16 copy) ∥ degree count.
    // gemm0 no longer reads dis -> legal to run before the scan.
    gemm0_count<<<GB + CEB, 256, 0, stream>>>(in_feat, lin_w, lin_b, h0, hbf,
                                              row, cnt, pos);
    scan_phase1<<<NBCH, 256, 0, stream>>>(cnt, bsum, N);
    scan_phase3<<<NBCH, 256, 0, stream>>>(cnt, bsum, row_start, deg_inv, dis, N, NBCH, E);
    fill_csr<<<CEB, 256, 0, stream>>>(row, col, row_start, pos, csr_col, E);

    // ---- prop step 0: aggregate -> conv + residual/LN/ReLU epilogue (h0, hbf in place) ----
    aggregate<<<WB, 256, 0, stream>>>(row_start, csr_col, dis, deg_inv, h0, hbf,
                                      agg_hi, agg_lo, N);
    gemm_conv<1><<<GB, 256, 0, stream>>>(agg_hi, agg_lo, conv_w, conv_b, h0, hbf,
                                         h0, deg_inv, root_emb,
                                         ln_gamma + HF, ln_beta + HF);

    // ---- prop step 1: aggregate -> conv + combine epilogue -> out ----
    aggregate<<<WB, 256, 0, stream>>>(row_start, csr_col, dis, deg_inv, h0, hbf,
                                      agg_hi, agg_lo, N);
    gemm_conv<2><<<GB, 256, 0, stream>>>(agg_hi, agg_lo, conv_w, conv_b, out, nullptr,
                                         h0, deg_inv, root_emb, nullptr, nullptr);
}